// Round 5
// baseline (356.200 us; speedup 1.0000x reference)
//
#include <hip/hip_runtime.h>

// RVQ round 7 = round-6 zero-VGPR LDS prefetch + 512-thread blocks + TB=2.
//
// Round-6 post-mortem: pipeline worked (spill gone, kernel ~122us) but only
// -5% -- x-load latency was NOT dominant. At ~2.75 waves/SIMD each wave-iter
// occupies ~17k cycles of wall-time vs a ~1.6k-cycle VALU body: all resident
// waves are stalled ~75% of the time. The limiter is wave COUNT.
// Cross-round fact: WG/CU is pinned at ~2.5-2.75 regardless of block size
// (r0/r2: 256thr -> 34% occ; r3: 512thr, same LDS -> 60% occ). The slot limit
// counts workgroups, not waves -> 512-thread blocks double resident waves.
// Round 3 proved it (60%) and only died of VGPR spill; TB=2 halves v[][] to
// 32 regs so the 512-thread body fits the 64-VGPR budget with slack.
//
// Per-wave pipeline (no __syncthreads in loop; per-wave buffers):
//   iter top: s_waitcnt vmcnt(3)  <- cur-buffer's 2 gl_lds retire; the 3
//                                    younger ops (2 stores + 1 atomic of
//                                    prev iter) stay in flight (FIFO retire)
//             issue 2 gl_lds -> buf^1 (next tokens), zero VGPR cost
//             ds_read xf, dots, reduce, argmin, blend, 2 stores + 1 atomic
// Prologue buffer drained by the setup __syncthreads (emits vmcnt(0)).
//
// Reduce-scatter scheme unchanged: lane l owns codeword k=h(l); v[j] holds
// k = j ^ h(l). 8x xor2 + 4x xor1 on DPP, 2x xor4 + 1x xor8 on ds_swizzle,
// then xor16 + shfl32 full sums. h(l) = bit1<<3 | bit0<<2 | bit2<<1 | bit3.
// Argmin: 4 min-steps over k-owner bits, ballot + ctz -> wave-uniform best k.

#define NH 3
#define NK 16
#define DHEAD 256
#define DFULL 768
#define TB 2
#define BLK 512
#define NW (BLK / 64)

typedef float f2 __attribute__((ext_vector_type(2)));
typedef float f4 __attribute__((ext_vector_type(4)));

__device__ __forceinline__ float dpp_xor1(float x) {
    return __builtin_bit_cast(float, __builtin_amdgcn_mov_dpp(
        __builtin_bit_cast(int, x), 0xB1, 0xF, 0xF, false));  // quad_perm(1,0,3,2)
}
__device__ __forceinline__ float dpp_xor2(float x) {
    return __builtin_bit_cast(float, __builtin_amdgcn_mov_dpp(
        __builtin_bit_cast(int, x), 0x4E, 0xF, 0xF, false));  // quad_perm(2,3,0,1)
}
__device__ __forceinline__ float swz_xor4(float x) {
    return __builtin_bit_cast(float, __builtin_amdgcn_ds_swizzle(
        __builtin_bit_cast(int, x), 0x101F));
}
__device__ __forceinline__ float swz_xor8(float x) {
    return __builtin_bit_cast(float, __builtin_amdgcn_ds_swizzle(
        __builtin_bit_cast(int, x), 0x201F));
}
__device__ __forceinline__ float swz_xor16(float x) {
    return __builtin_bit_cast(float, __builtin_amdgcn_ds_swizzle(
        __builtin_bit_cast(int, x), 0x401F));
}

// async global->LDS, 16B/lane, dest = wave-uniform base + lane*16
__device__ __forceinline__ void async_ld16(const float* g, float* l) {
    __builtin_amdgcn_global_load_lds(
        (const __attribute__((address_space(1))) unsigned int*)g,
        (__attribute__((address_space(3))) unsigned int*)l, 16, 0, 0);
}

__global__ __launch_bounds__(BLK) void rvq_head_kernel(
    const float* __restrict__ x,
    const float* __restrict__ cb,
    const float* __restrict__ alphap,
    float* __restrict__ out,
    float* __restrict__ codef,
    int tok_per_block)
{
    const int h = blockIdx.y;
    __shared__ float lc[NK * DHEAD];         // 16 KB codebook, head h
    __shared__ float xbuf[2][NW][TB][256];   // 32 KB: per-wave double buffer
    __shared__ float lps[256];               // norm partials
    __shared__ float lcn[NK];                // codeword squared norms

    const int tid  = threadIdx.x;
    const int lane = tid & 63;
    const int wid  = tid >> 6;

    const int t_base = blockIdx.x * tok_per_block;
    const int t_end  = t_base + tok_per_block;
    const int step   = NW * TB;              // 16 tokens per block-iteration

    const f4* x4 = (const f4*)x;
    f4* out4     = (f4*)out;

    // prologue: issue buffer-0 prefetch immediately (drained by syncthreads)
    int t0 = t_base + wid * TB;
    #pragma unroll
    for (int t = 0; t < TB; ++t)
        async_ld16((const float*)&x4[(size_t)(t0 + t) * (DFULL / 4) + h * 64 + lane],
                   &xbuf[0][wid][t][0]);

    // stage head-h codebook (coalesced float4, 2 per thread at BLK=512)
    const f4* cb4 = (const f4*)(cb + (size_t)h * NK * DHEAD);
    f4* lc4w = (f4*)lc;
    #pragma unroll
    for (int i = 0; i < 2; ++i) lc4w[tid + i * BLK] = cb4[tid + i * BLK];

    // codeword norm partials: thread i<256 -> row i>>4, 16 dims at (i&15)*16
    if (tid < 256) {
        const int r = tid >> 4, dd = (tid & 15) * 16;
        const f4* p = (const f4*)(cb + (size_t)h * NK * DHEAD + r * DHEAD + dd);
        float s = 0.f;
        #pragma unroll
        for (int q = 0; q < 4; ++q) {
            f4 c = p[q];
            s += c.x * c.x + c.y * c.y + c.z * c.z + c.w * c.w;
        }
        lps[tid] = s;
    }
    __syncthreads();
    if (tid < NK) {
        float s = 0.f;
        #pragma unroll
        for (int q = 0; q < 16; ++q) s += lps[tid * 16 + q];
        lcn[tid] = s;
    }
    __syncthreads();   // emits s_waitcnt vmcnt(0): buffer 0 is complete here

    // k owned by this lane after reduce-scatter
    const int hl = (((lane >> 1) & 1) << 3) | ((lane & 1) << 2)
                 | (((lane >> 2) & 1) << 1) | ((lane >> 3) & 1);
    const float cn_l  = lcn[hl];
    const float alpha = alphap[0];
    const float beta  = 1.0f - alpha;
    const float kscale = (float)(1 << (4 * h));

    const f4* lc4 = (const f4*)lc;

    int cur = 0;
    while (t0 < t_end) {
        const int t1 = t0 + step;

        // wait for buffer `cur` (2 gl_lds issued last iter, oldest in FIFO);
        // the 3 younger ops (2 stores + 1 atomic of last iter) may remain.
        asm volatile("s_waitcnt vmcnt(3)" ::: "memory");

        // issue next-buffer prefetch (zero-VGPR async copy)
        if (t1 < t_end) {
            #pragma unroll
            for (int t = 0; t < TB; ++t)
                async_ld16((const float*)&x4[(size_t)(t1 + t) * (DFULL / 4)
                                             + h * 64 + lane],
                           &xbuf[cur ^ 1][wid][t][0]);
        }
        asm volatile("" ::: "memory");  // keep stores/atomic below the loads

        // xf from LDS (per-wave region, conflict-free: lane*16B)
        f4 xf[TB];
        #pragma unroll
        for (int t = 0; t < TB; ++t)
            xf[t] = *(const f4*)&xbuf[cur][wid][t][lane * 4];

        // partial dots: v[t][j] = <x4_lane, c[j^hl]_lane> (packed fp32 fma)
        float v[TB][NK];
        #pragma unroll
        for (int j = 0; j < NK; ++j) {
            f4 c = lc4[((j ^ hl) << 6) | lane];
            #pragma unroll
            for (int t = 0; t < TB; ++t) {
                f2 p = (f2){xf[t].x, xf[t].y} * (f2){c.x, c.y};
                p += (f2){xf[t].z, xf[t].w} * (f2){c.z, c.w};
                v[t][j] = p.x + p.y;
            }
        }

        // recursive-halving reduce-scatter + full sum
        #pragma unroll
        for (int t = 0; t < TB; ++t) {
            #pragma unroll
            for (int j = 0; j < 8; ++j) v[t][j] += dpp_xor2(v[t][j + 8]);
            #pragma unroll
            for (int j = 0; j < 4; ++j) v[t][j] += dpp_xor1(v[t][j + 4]);
            #pragma unroll
            for (int j = 0; j < 2; ++j) v[t][j] += swz_xor4(v[t][j + 2]);
            v[t][0] += swz_xor8(v[t][1]);
            v[t][0] += swz_xor16(v[t][0]);
            v[t][0] += __shfl_xor(v[t][0], 32);
        }

        // score, argmin, blend, store (round-2 form)
        float bif[TB];
        #pragma unroll
        for (int t = 0; t < TB; ++t) {
            const float sc = cn_l - 2.0f * v[t][0];
            float m = sc;
            m = fminf(m, dpp_xor1(m));
            m = fminf(m, dpp_xor2(m));
            m = fminf(m, swz_xor4(m));
            m = fminf(m, swz_xor8(m));
            const unsigned long long mask = __ballot(sc == m);
            const int lmin = __builtin_ctzll(mask);
            const int bi = (((lmin >> 1) & 1) << 3) | ((lmin & 1) << 2)
                         | (((lmin >> 2) & 1) << 1) | ((lmin >> 3) & 1);
            const f4 c = lc4[(bi << 6) | lane];
            f4 o;
            o.x = alpha * xf[t].x + beta * c.x;
            o.y = alpha * xf[t].y + beta * c.y;
            o.z = alpha * xf[t].z + beta * c.z;
            o.w = alpha * xf[t].w + beta * c.w;
            out4[(size_t)(t0 + t) * (DFULL / 4) + h * 64 + lane] = o;
            bif[t] = (float)bi * kscale;
        }

        // batched code atomics: lanes 0..1 carry the 2 wave-uniform codes
        // (exactly 1 VMEM op -> the vmcnt(3) count above stays exact)
        const float mya = (lane == 0) ? bif[0] : bif[1];
        if (lane < TB) atomicAdd(codef + t0 + lane, mya);

        t0 = t1;
        cur ^= 1;
    }
}

extern "C" void kernel_launch(void* const* d_in, const int* in_sizes, int n_in,
                              void* d_out, int out_size, void* d_ws, size_t ws_size,
                              hipStream_t stream) {
    const float* x      = (const float*)d_in[0];
    const float* cb     = (const float*)d_in[1];
    const float* alphap = (const float*)d_in[2];
    const int n_tokens  = in_sizes[0] / DFULL;            // 65536
    float* out   = (float*)d_out;
    float* codef = out + (size_t)n_tokens * DFULL;        // second output

    // code accumulated via fp32 atomicAdd across the 3 head-grids -> zero it
    hipMemsetAsync(codef, 0, (size_t)n_tokens * sizeof(float), stream);

    const int tok_per_block = 256;
    const int grid_x = n_tokens / tok_per_block;          // 256 -> 768 blocks
    dim3 grid(grid_x, NH);
    rvq_head_kernel<<<grid, BLK, 0, stream>>>(x, cb, alphap, out, codef,
                                              tok_per_block);
}